// Round 1
// baseline (157.630 us; speedup 1.0000x reference)
//
#include <hip/hip_runtime.h>
#include <math.h>

#define HH 256
#define WW 256
#define BB 2
#define NN 256
#define ALPHA0 0.025f
#define BETA_ 2.0f
#define EPSF 1e-8f
#define PI_F 3.14159265358979323846f

// ws float layout:
//  [0..1]  alpha per batch
//  [2..3]  scale per batch
//  [4..5]  zmax encoded keys (unsigned, ordered-float encoding)
//  [16 .. 16 + B*N*20)          gaussian tables (20 floats each)
//  [PIX_OFF .. PIX_OFF+B*HW*4)  per-pixel accum float4 (rgb, wsum)
#define GD_OFF 16
#define GD_STRIDE 20
#define PIX_OFF (GD_OFF + BB * NN * GD_STRIDE)   // 10256 floats -> 16B aligned

__device__ __forceinline__ unsigned fkey(float f) {
    unsigned u = __float_as_uint(f);
    return u ^ ((unsigned)((int)u >> 31) | 0x80000000u);
}
__device__ __forceinline__ float funkey(unsigned k) {
    unsigned u = (k & 0x80000000u) ? (k ^ 0x80000000u) : ~k;
    return __uint_as_float(u);
}

// ---------------- Kernel 1: per-batch scale/alpha + per-gaussian tables ----
__global__ void __launch_bounds__(256) prep_kernel(const float* __restrict__ mu,
                                                   const float* __restrict__ rho,
                                                   const float* __restrict__ lambd,
                                                   const float* __restrict__ app,
                                                   float* __restrict__ ws) {
    const int b = blockIdx.x;
    const int t = threadIdx.x;
    __shared__ float red[256];
    __shared__ float s_scale;

    // min over lam (N*3 = 768 values)
    const float* lamB = lambd + b * NN * 3;
    float m = 3.4e38f;
    for (int i = t; i < NN * 3; i += 256) m = fminf(m, lamB[i]);
    red[t] = m;
    __syncthreads();
    for (int s = 128; s > 0; s >>= 1) {
        if (t < s) red[t] = fminf(red[t], red[t + s]);
        __syncthreads();
    }
    if (t == 0) {
        float minlam = red[0];
        float ls = ceilf(log10f(fmaxf(minlam, 1e-6f)));
        float scale = powf(10.0f, ls);
        ws[0 + b] = ALPHA0 * scale;
        ws[2 + b] = scale;
        ((unsigned*)ws)[4 + b] = fkey(-INFINITY);  // init zmax atomic slot
        s_scale = scale;
    }
    __syncthreads();
    const float scale = s_scale;

    // one gaussian per thread (N == blockDim)
    const int n = t;
    const float* rp = rho + (size_t)(b * NN + n) * 9;
    const float* mp = mu + (size_t)(b * NN + n) * 3;
    const float* lp = lambd + (size_t)(b * NN + n) * 3;
    const float* ap = app + (size_t)(b * NN + n) * 3;
    float r00 = rp[0], r01 = rp[1], r02 = rp[2];
    float r10 = rp[3], r11 = rp[4], r12 = rp[5];
    float r20 = rp[6], r21 = rp[7], r22 = rp[8];
    float m0 = mp[0], m1 = mp[1], m2 = mp[2];
    // rho_mu[k] = sum_c rho[c][k] * mu[c]
    float rm0 = r00 * m0 + r10 * m1 + r20 * m2;
    float rm1 = r01 * m0 + r11 * m1 + r21 * m2;
    float rm2 = r02 * m0 + r12 * m1 + r22 * m2;
    float li0 = scale / fmaxf(lp[0], EPSF);
    float li1 = scale / fmaxf(lp[1], EPSF);
    float li2 = scale / fmaxf(lp[2], EPSF);
    float g0 = li0 * rm0, g1 = li1 * rm1, g2 = li2 * rm2;
    float msm = g0 * rm0 + g1 * rm1 + g2 * rm2;

    float* gd = ws + GD_OFF + (size_t)(b * NN + n) * GD_STRIDE;
    gd[0] = r00; gd[1] = r01; gd[2] = r02;
    gd[3] = r10; gd[4] = r11; gd[5] = r12;
    gd[6] = r20; gd[7] = r21; gd[8] = r22;
    gd[9] = li0; gd[10] = li1; gd[11] = li2;
    gd[12] = g0; gd[13] = g1; gd[14] = g2;
    gd[15] = msm;
    gd[16] = ap[0]; gd[17] = ap[1]; gd[18] = ap[2];
    gd[19] = 0.0f;
}

// ---------------- Kernel 2: heavy pass — per-pixel accum + z-max ----------
__global__ void __launch_bounds__(256) accum_kernel(const float* __restrict__ K,
                                                    float* __restrict__ ws) {
    const int b = blockIdx.y;
    const int t = threadIdx.x;
    __shared__ float gd[NN * GD_STRIDE];
    __shared__ float wred[4];

    const float* src = ws + GD_OFF + (size_t)b * NN * GD_STRIDE;
    for (int i = t; i < NN * GD_STRIDE; i += 256) gd[i] = src[i];
    __syncthreads();

    const float alpha = ws[b];
    const float inv_alpha = 1.0f / alpha;
    const float a = 0.5f * sqrtf(PI_F * alpha);
    const float* Kb = K + b * 9;
    const float fx = Kb[0], cx = Kb[2], fy = Kb[4], cy = Kb[5];

    const int pix = blockIdx.x * 256 + t;
    const int px = pix & (WW - 1);
    const int py = pix >> 8;
    float rx = ((float)px - cx) / fx;
    float ry = ((float)py - cy) / fy;
    float nrm = sqrtf(rx * rx + ry * ry + 1.0f);
    float inn = 1.0f / nrm;
    const float r0 = rx * inn, r1 = ry * inn, r2 = inn;

    float wsum = 0.0f, c0 = 0.0f, c1 = 0.0f, c2 = 0.0f;
    float zmax = -INFINITY;

#pragma unroll 4
    for (int n = 0; n < NN; ++n) {
        const float* g = &gd[n * GD_STRIDE];
        // rho^T r
        float rr0 = g[0] * r0 + g[3] * r1 + g[6] * r2;
        float rr1 = g[1] * r0 + g[4] * r1 + g[7] * r2;
        float rr2 = g[2] * r0 + g[5] * r1 + g[8] * r2;
        float rsr = g[9] * rr0 * rr0 + g[10] * rr1 * rr1 + g[11] * rr2 * rr2;
        float rsm = g[12] * rr0 + g[13] * rr1 + g[14] * rr2;
        float rcp = 1.0f / fmaxf(rsr, EPSF);
        float z = rsm * rcp;
        zmax = fmaxf(zmax, z);
        float d = g[15] - rsm * z;                       // msm - rsm^2/max(rsr,eps)
        float ee = expf(fminf(-d * inv_alpha, 8.0f));    // outer 1e8 clamp is dead
        float bb = fmaxf(sqrtf(fmaxf(rsr, 0.0f)), EPSF);
        float z2 = z * z;
        float z4 = z2 * z2;
        float w = (a * ee) / (bb * (1.0f + z4));         // >= 0 always
        wsum += w;
        c0 += w * g[16];
        c1 += w * g[17];
        c2 += w * g[18];
    }

    float4 acc = make_float4(c0, c1, c2, wsum);
    ((float4*)(ws + PIX_OFF))[(size_t)b * (HH * WW) + pix] = acc;

    // block-reduce zmax -> per-batch atomic
    for (int off = 32; off >= 1; off >>= 1)
        zmax = fmaxf(zmax, __shfl_down(zmax, off, 64));
    if ((t & 63) == 0) wred[t >> 6] = zmax;
    __syncthreads();
    if (t == 0) {
        float zm = fmaxf(fmaxf(wred[0], wred[1]), fmaxf(wred[2], wred[3]));
        atomicMax((unsigned*)ws + 4 + b, fkey(zm));
    }
}

// ---------------- Kernel 3: epilogue — background + normalize + write -----
__global__ void __launch_bounds__(256) finish_kernel(const float* __restrict__ bg_app,
                                                     float* __restrict__ out,
                                                     const float* __restrict__ ws) {
    const int b = blockIdx.y;
    const int pix = blockIdx.x * 256 + threadIdx.x;

    const float alpha = ws[b];
    const float a = 0.5f * sqrtf(PI_F * alpha);
    const float zmax = funkey(((const unsigned*)ws)[4 + b]);
    const float zbg = BETA_ * zmax;
    const float zb2 = zbg * zbg;
    const float zb4 = zb2 * zb2;
    const float wbg = a / (1.0f + zb4);   // bg_int = a (erfc clipped to 1)

    float4 acc = ((const float4*)(ws + PIX_OFF))[(size_t)b * (HH * WW) + pix];
    float inv = 1.0f / fmaxf(acc.w + wbg, EPSF);
    float b0 = bg_app[b * 3 + 0], b1 = bg_app[b * 3 + 1], b2 = bg_app[b * 3 + 2];

    const int hw = HH * WW;
    const int base = (b * 3) * hw + pix;
    out[base] = (acc.x + wbg * b0) * inv;
    out[base + hw] = (acc.y + wbg * b1) * inv;
    out[base + 2 * hw] = (acc.z + wbg * b2) * inv;
}

extern "C" void kernel_launch(void* const* d_in, const int* in_sizes, int n_in,
                              void* d_out, int out_size, void* d_ws, size_t ws_size,
                              hipStream_t stream) {
    const float* mu = (const float*)d_in[0];
    const float* rho = (const float*)d_in[1];
    const float* lambd = (const float*)d_in[2];
    const float* app = (const float*)d_in[3];
    const float* bg = (const float*)d_in[4];
    const float* K = (const float*)d_in[5];
    float* ws = (float*)d_ws;
    float* out = (float*)d_out;

    hipLaunchKernelGGL(prep_kernel, dim3(BB), dim3(256), 0, stream, mu, rho, lambd, app, ws);
    dim3 grid(HH * WW / 256, BB);
    hipLaunchKernelGGL(accum_kernel, grid, dim3(256), 0, stream, K, ws);
    hipLaunchKernelGGL(finish_kernel, grid, dim3(256), 0, stream, bg, out, ws);
}

// Round 3
// 99.283 us; speedup vs baseline: 1.5877x; 1.5877x over previous
//
#include <hip/hip_runtime.h>
#include <math.h>

#define HH 256
#define WW 256
#define BB 2
#define NN 256
#define SPLIT 2
#define GPB (NN / SPLIT)          // gaussians per block half
#define ALPHA0 0.025f
#define BETA_ 2.0f
#define EPSF 1e-8f
#define PI_F 3.14159265358979323846f

// ws float layout:
//  [0..1]   alpha per batch
//  [2..3]   scale per batch
//  [4..5]   zmax encoded keys (unsigned, ordered-float encoding)
//  [16 .. 16 + B*N*16)            gaussian tables (16 floats each, float4-packed)
//  [PIX_OFF .. +B*SPLIT*HW*4)     per-pixel partial accum float4 (rgb, wsum)
#define GD_OFF 16
#define GD_STRIDE 16
#define PIX_OFF (GD_OFF + BB * NN * GD_STRIDE)   // 16 + 8192 = 8208 floats (16B aligned)

__device__ __forceinline__ unsigned fkey(float f) {
    unsigned u = __float_as_uint(f);
    return u ^ ((unsigned)((int)u >> 31) | 0x80000000u);
}
__device__ __forceinline__ float funkey(unsigned k) {
    unsigned u = (k & 0x80000000u) ? (k ^ 0x80000000u) : ~k;
    return __uint_as_float(u);
}

// ---------------- Kernel 1: per-batch scale/alpha + per-gaussian tables ----
// table layout per gaussian (16 floats):
//  [0..3]  M00 M11 M22 M01     (M = rho diag(li) rho^T, symmetric)
//  [4..7]  M02 M12 v0  v1      (v = rho * (li*rho_mu))
//  [8..11] v2  msm  app0 app1
//  [12..15] app2 0 0 0
__global__ void __launch_bounds__(256) prep_kernel(const float* __restrict__ mu,
                                                   const float* __restrict__ rho,
                                                   const float* __restrict__ lambd,
                                                   const float* __restrict__ app,
                                                   float* __restrict__ ws) {
    const int b = blockIdx.x;
    const int t = threadIdx.x;
    __shared__ float red[256];
    __shared__ float s_scale;

    // min over lam (N*3 = 768 values)
    const float* lamB = lambd + b * NN * 3;
    float m = 3.4e38f;
    for (int i = t; i < NN * 3; i += 256) m = fminf(m, lamB[i]);
    red[t] = m;
    __syncthreads();
    for (int s = 128; s > 0; s >>= 1) {
        if (t < s) red[t] = fminf(red[t], red[t + s]);
        __syncthreads();
    }
    if (t == 0) {
        float minlam = red[0];
        float ls = ceilf(log10f(fmaxf(minlam, 1e-6f)));
        float scale = powf(10.0f, ls);
        ws[0 + b] = ALPHA0 * scale;
        ws[2 + b] = scale;
        ((unsigned*)ws)[4 + b] = fkey(-INFINITY);  // init zmax atomic slot
        s_scale = scale;
    }
    __syncthreads();
    const float scale = s_scale;

    // one gaussian per thread (N == blockDim)
    const int n = t;
    const float* rp = rho + (size_t)(b * NN + n) * 9;
    const float* mp = mu + (size_t)(b * NN + n) * 3;
    const float* lp = lambd + (size_t)(b * NN + n) * 3;
    const float* ap = app + (size_t)(b * NN + n) * 3;
    float r00 = rp[0], r01 = rp[1], r02 = rp[2];
    float r10 = rp[3], r11 = rp[4], r12 = rp[5];
    float r20 = rp[6], r21 = rp[7], r22 = rp[8];
    float m0 = mp[0], m1 = mp[1], m2 = mp[2];
    // rho_mu[k] = sum_c rho[c][k] * mu[c]
    float rm0 = r00 * m0 + r10 * m1 + r20 * m2;
    float rm1 = r01 * m0 + r11 * m1 + r21 * m2;
    float rm2 = r02 * m0 + r12 * m1 + r22 * m2;
    float li0 = scale / fmaxf(lp[0], EPSF);
    float li1 = scale / fmaxf(lp[1], EPSF);
    float li2 = scale / fmaxf(lp[2], EPSF);
    float g0 = li0 * rm0, g1 = li1 * rm1, g2 = li2 * rm2;
    float msm = g0 * rm0 + g1 * rm1 + g2 * rm2;

    float M00 = li0 * r00 * r00 + li1 * r01 * r01 + li2 * r02 * r02;
    float M11 = li0 * r10 * r10 + li1 * r11 * r11 + li2 * r12 * r12;
    float M22 = li0 * r20 * r20 + li1 * r21 * r21 + li2 * r22 * r22;
    float M01 = li0 * r00 * r10 + li1 * r01 * r11 + li2 * r02 * r12;
    float M02 = li0 * r00 * r20 + li1 * r01 * r21 + li2 * r02 * r22;
    float M12 = li0 * r10 * r20 + li1 * r11 * r21 + li2 * r12 * r22;
    float v0 = r00 * g0 + r01 * g1 + r02 * g2;
    float v1 = r10 * g0 + r11 * g1 + r12 * g2;
    float v2 = r20 * g0 + r21 * g1 + r22 * g2;

    float* gd = ws + GD_OFF + (size_t)(b * NN + n) * GD_STRIDE;
    gd[0] = M00; gd[1] = M11; gd[2] = M22; gd[3] = M01;
    gd[4] = M02; gd[5] = M12; gd[6] = v0;  gd[7] = v1;
    gd[8] = v2;  gd[9] = msm; gd[10] = ap[0]; gd[11] = ap[1];
    gd[12] = ap[2]; gd[13] = 0.0f; gd[14] = 0.0f; gd[15] = 0.0f;
}

// ---------------- Kernel 2: heavy pass — per-pixel partial accum + z-max ---
__global__ void __launch_bounds__(256) accum_kernel(const float* __restrict__ K,
                                                    float* __restrict__ ws) {
    const int by = blockIdx.y;           // b*SPLIT + half
    const int b = by >> 1;
    const int h = by & 1;
    const int t = threadIdx.x;
    __shared__ float4 gd[GPB * 4];       // 128 gaussians * 16 floats = 8 KB
    __shared__ float wred[4];

    const float4* src = (const float4*)(ws + GD_OFF) + (size_t)(b * NN + h * GPB) * 4;
    gd[t] = src[t];
    gd[t + 256] = src[t + 256];

    const float alpha = ws[b];
    const float inv_alpha = 1.0f / alpha;
    const float* Kb = K + b * 9;
    const float fx = Kb[0], cx = Kb[2], fy = Kb[4], cy = Kb[5];
    __syncthreads();

    const int pix = blockIdx.x * 256 + t;
    const int px = pix & (WW - 1);
    const int py = pix >> 8;
    float rx = ((float)px - cx) / fx;
    float ry = ((float)py - cy) / fy;
    float inn = __builtin_amdgcn_rsqf(rx * rx + ry * ry + 1.0f);
    const float r0 = rx * inn, r1 = ry * inn, r2 = inn;
    const float q0 = r0 * r0, q1 = r1 * r1, q2 = r2 * r2;
    const float q3 = 2.0f * r0 * r1, q4 = 2.0f * r0 * r2, q5 = 2.0f * r1 * r2;

    float wsum = 0.0f, c0 = 0.0f, c1 = 0.0f, c2 = 0.0f;
    float zmax = -INFINITY;

#pragma unroll 4
    for (int n = 0; n < GPB; ++n) {
        float4 A = gd[n * 4 + 0];   // M00 M11 M22 M01
        float4 Bv = gd[n * 4 + 1];  // M02 M12 v0  v1
        float4 C = gd[n * 4 + 2];   // v2  msm app0 app1
        float4 D = gd[n * 4 + 3];   // app2 - - -

        float rsr = fmaf(A.x, q0, fmaf(A.y, q1, fmaf(A.z, q2,
                    fmaf(A.w, q3, fmaf(Bv.x, q4, Bv.y * q5)))));
        float rsm = fmaf(Bv.z, r0, fmaf(Bv.w, r1, C.x * r2));
        float rsrc = fmaxf(rsr, EPSF);
        float rsq = __builtin_amdgcn_rsqf(rsrc);   // 1/sqrt(rsr)
        float rcp = rsq * rsq;                     // 1/rsr
        float z = rsm * rcp;
        zmax = fmaxf(zmax, z);
        float d = fmaf(-rsm, z, C.y);              // msm - rsm^2/rsr
        float ee = __expf(fminf(-d * inv_alpha, 8.0f));
        float z2 = z * z;
        float z4 = z2 * z2;
        float den = __builtin_amdgcn_rcpf(1.0f + z4);
        float w = ee * rsq * den;                  // 'a' factored out (applied in finish)
        wsum += w;
        c0 = fmaf(w, C.z, c0);
        c1 = fmaf(w, C.w, c1);
        c2 = fmaf(w, D.x, c2);
    }

    ((float4*)(ws + PIX_OFF))[(size_t)by * (HH * WW) + pix] =
        make_float4(c0, c1, c2, wsum);

    // block-reduce zmax -> per-batch atomic
    for (int off = 32; off >= 1; off >>= 1)
        zmax = fmaxf(zmax, __shfl_down(zmax, off, 64));
    if ((t & 63) == 0) wred[t >> 6] = zmax;
    __syncthreads();
    if (t == 0) {
        float zm = fmaxf(fmaxf(wred[0], wred[1]), fmaxf(wred[2], wred[3]));
        atomicMax((unsigned*)ws + 4 + b, fkey(zm));
    }
}

// ---------------- Kernel 3: epilogue — background + normalize + write -----
__global__ void __launch_bounds__(256) finish_kernel(const float* __restrict__ bg_app,
                                                     float* __restrict__ out,
                                                     const float* __restrict__ ws) {
    const int b = blockIdx.y;
    const int tid = blockIdx.x * 256 + threadIdx.x;
    const int p = tid * 4;                    // 4 consecutive pixels per thread

    const float alpha = ws[b];
    const float a = 0.5f * sqrtf(PI_F * alpha);
    const float zmax = funkey(((const unsigned*)ws)[4 + b]);
    const float zbg = BETA_ * zmax;
    const float zb2 = zbg * zbg;
    const float zb4 = zb2 * zb2;
    const float wbg = a / (1.0f + zb4);       // bg_int = a (erfc clipped to 1)
    const float b0 = bg_app[b * 3 + 0], b1 = bg_app[b * 3 + 1], b2 = bg_app[b * 3 + 2];

    const int hw = HH * WW;
    const float4* acc0 = (const float4*)(ws + PIX_OFF) + (size_t)(b * SPLIT) * hw;
    const float4* acc1 = acc0 + hw;

    float4 o0, o1, o2;
    float* po0 = &o0.x; float* po1 = &o1.x; float* po2 = &o2.x;
    for (int j = 0; j < 4; ++j) {
        float4 s0 = acc0[p + j];
        float4 s1 = acc1[p + j];
        float sw = a * (s0.w + s1.w) + wbg;
        float inv = 1.0f / fmaxf(sw, EPSF);
        po0[j] = (a * (s0.x + s1.x) + wbg * b0) * inv;
        po1[j] = (a * (s0.y + s1.y) + wbg * b1) * inv;
        po2[j] = (a * (s0.z + s1.z) + wbg * b2) * inv;
    }
    float4* outbase = (float4*)(out + (size_t)(b * 3) * hw + p);
    outbase[0] = o0;
    *(float4*)(out + (size_t)(b * 3 + 1) * hw + p) = o1;
    *(float4*)(out + (size_t)(b * 3 + 2) * hw + p) = o2;
}

extern "C" void kernel_launch(void* const* d_in, const int* in_sizes, int n_in,
                              void* d_out, int out_size, void* d_ws, size_t ws_size,
                              hipStream_t stream) {
    const float* mu = (const float*)d_in[0];
    const float* rho = (const float*)d_in[1];
    const float* lambd = (const float*)d_in[2];
    const float* app = (const float*)d_in[3];
    const float* bg = (const float*)d_in[4];
    const float* K = (const float*)d_in[5];
    float* ws = (float*)d_ws;
    float* out = (float*)d_out;

    hipLaunchKernelGGL(prep_kernel, dim3(BB), dim3(256), 0, stream, mu, rho, lambd, app, ws);
    dim3 grid(HH * WW / 256, BB * SPLIT);
    hipLaunchKernelGGL(accum_kernel, grid, dim3(256), 0, stream, K, ws);
    dim3 fgrid(HH * WW / (256 * 4), BB);
    hipLaunchKernelGGL(finish_kernel, fgrid, dim3(256), 0, stream, bg, out, ws);
}